// Round 10
// baseline (529.038 us; speedup 1.0000x reference)
//
#include <hip/hip_runtime.h>

#define NEPS 1e-5f

__device__ inline unsigned int bfpack(float a, float b) {
  unsigned int ua = __float_as_uint(a), ub = __float_as_uint(b);
  ua += 0x7fff + ((ua >> 16) & 1);
  ub += 0x7fff + ((ub >> 16) & 1);
  return (ua >> 16) | (ub & 0xffff0000u);
}
__device__ inline float bflo(unsigned int u) { return __uint_as_float(u << 16); }
__device__ inline float bfhi(unsigned int u) { return __uint_as_float(u & 0xffff0000u); }

// inclusive scan of v over 256 threads (4 waves); tmp = LDS int[4]
__device__ inline int blockScan256(int v, int t, int* tmp) {
  int lane = t & 63, w = t >> 6;
  #pragma unroll
  for (int off = 1; off < 64; off <<= 1) {
    int u = __shfl_up(v, off);
    if (lane >= off) v += u;
  }
  if (lane == 63) tmp[w] = v;
  __syncthreads();
  int add = 0;
  for (int k = 0; k < w; k++) add += tmp[k];
  return v + add;
}

// ---------------- CSR build via MSB bucket sort (no per-edge global atomics) ----------------
__global__ __launch_bounds__(256) void k_hist(const int* __restrict__ ei,
                                              int* __restrict__ gh_pad, int E_) {
  __shared__ int h[256];
  int t = threadIdx.x;
  h[t] = 0;
  __syncthreads();
  int i = blockIdx.x * 256 + t;
  int stride = gridDim.x * 256;
  for (int e = i; e < E_; e += stride) atomicAdd(&h[ei[E_ + e] >> 8], 1);
  __syncthreads();
  int c = h[t];
  if (c) atomicAdd(&gh_pad[t * 16], c);
}

__global__ __launch_bounds__(256) void k_scan2(const int* __restrict__ gh_pad,
                                               int* __restrict__ b_base,
                                               int* __restrict__ cur_pad, int E_) {
  __shared__ int tmp[4];
  int t = threadIdx.x;
  int c = gh_pad[t * 16];
  int incl = blockScan256(c, t, tmp);
  int excl = incl - c;
  b_base[t] = excl;
  cur_pad[t * 16] = excl;
  if (t == 255) b_base[256] = incl;
}

__global__ __launch_bounds__(256) void k_part(const int* __restrict__ ei,
                                              int* __restrict__ cur_pad,
                                              unsigned int* __restrict__ kp, int E_) {
  __shared__ int lh[256], lbase[256];
  int t = threadIdx.x;
  int start = blockIdx.x * 8192;
  int end = min(start + 8192, E_);
  lh[t] = 0;
  __syncthreads();
  for (int e = start + t; e < end; e += 256) atomicAdd(&lh[ei[E_ + e] >> 8], 1);
  __syncthreads();
  int c = lh[t];
  if (c) lbase[t] = atomicAdd(&cur_pad[t * 16], c);
  __syncthreads();
  lh[t] = 0;
  __syncthreads();
  for (int e = start + t; e < end; e += 256) {
    int d = ei[E_ + e], s = ei[e];
    int bin = d >> 8;
    int slot = atomicAdd(&lh[bin], 1);
    kp[lbase[bin] + slot] = ((unsigned int)d << 16) | (unsigned int)s;
  }
}

__global__ __launch_bounds__(256) void k_bucket(const unsigned int* __restrict__ kp,
                                                const int* __restrict__ b_base,
                                                unsigned short* __restrict__ csr16,
                                                int* __restrict__ row_ptr, int* __restrict__ cnt,
                                                const float* __restrict__ x,
                                                float* __restrict__ dis, float4* __restrict__ xp,
                                                float* __restrict__ stats, int N_) {
  __shared__ int cur[256], offL[256], tmp[4];
  __shared__ float rs[4][8];
  int t = threadIdx.x, b = blockIdx.x;
  int seg0 = b_base[b], seg1 = b_base[b + 1];
  cur[t] = 0;
  __syncthreads();
  for (int e = seg0 + t; e < seg1; e += 256) atomicAdd(&cur[(kp[e] >> 16) & 255], 1);
  __syncthreads();
  int c = cur[t];
  int incl = blockScan256(c, t, tmp);
  offL[t] = incl - c;
  __syncthreads();
  cur[t] = 0;
  __syncthreads();
  for (int e = seg0 + t; e < seg1; e += 256) {
    unsigned int v = kp[e];
    int dl = (v >> 16) & 255;
    int slot = atomicAdd(&cur[dl], 1);
    csr16[seg0 + offL[dl] + slot] = (unsigned short)(v & 0xffffu);
  }
  int n = b * 256 + t;
  float s1[3] = {0, 0, 0}, s2[3] = {0, 0, 0};
  if (n < N_) {
    row_ptr[n] = seg0 + offL[t];
    cnt[n] = c;
    float dg = (float)c + 1.0f;
    float ds_ = rsqrtf(dg);
    dis[n] = ds_;
    float x0 = x[n * 3 + 0], x1 = x[n * 3 + 1], x2 = x[n * 3 + 2];
    float4 v; v.x = ds_ * x0; v.y = ds_ * x1; v.z = ds_ * x2; v.w = ds_;
    xp[n] = v;
    s1[0] = x0; s1[1] = x1; s1[2] = x2;
    s2[0] = x0 * x0; s2[1] = x1 * x1; s2[2] = x2 * x2;
  }
  #pragma unroll
  for (int cc = 0; cc < 3; cc++) {
    for (int off = 32; off > 0; off >>= 1) {
      s1[cc] += __shfl_down(s1[cc], off);
      s2[cc] += __shfl_down(s2[cc], off);
    }
  }
  int lane = t & 63, w = t >> 6;
  if (lane == 0) {
    rs[w][0] = s1[0]; rs[w][1] = s1[1]; rs[w][2] = s1[2]; rs[w][3] = 0.f;
    rs[w][4] = s2[0]; rs[w][5] = s2[1]; rs[w][6] = s2[2]; rs[w][7] = 0.f;
  }
  __syncthreads();
  if (t < 8 && t != 3 && t != 7) {
    float a = rs[0][t] + rs[1][t] + rs[2][t] + rs[3][t];
    atomicAdd(&stats[t], a);
  }
}

// ---------------- fused layer 1: BN0-fold + gather(xp) + GEMM(3->128) + relu + stats ----------------
__global__ __launch_bounds__(256) void k_layer1(const float4* __restrict__ xp,
                                                const unsigned short* __restrict__ csr16,
                                                const int* __restrict__ row_ptr,
                                                const int* __restrict__ cnt,
                                                const float* __restrict__ stats,
                                                const float* __restrict__ g0,
                                                const float* __restrict__ b0,
                                                const float* __restrict__ W1,
                                                const float* __restrict__ b1,
                                                unsigned short* __restrict__ yb,
                                                float* __restrict__ Sp,
                                                int N_) {
  __shared__ float wl[5 * 128];
  int t = threadIdx.x;
  float a_[3], dd_[3];
  #pragma unroll
  for (int c = 0; c < 3; c++) {
    float m = stats[c] / N_;
    float v = stats[4 + c] / N_ - m * m;
    float sc = g0[c] * rsqrtf(v + NEPS);
    a_[c] = sc; dd_[c] = b0[c] - m * sc;
  }
  for (int i = t; i < 384; i += 256) wl[i] = a_[i >> 7] * W1[i];
  for (int i = t; i < 128; i += 256) {
    wl[384 + i] = fmaf(dd_[0], W1[i], fmaf(dd_[1], W1[128 + i], dd_[2] * W1[256 + i]));
    wl[512 + i] = b1[i];
  }
  __syncthreads();
  int lane = t & 63, w = t >> 6;
  int c0 = lane * 2;
  float2 w0 = *(const float2*)&wl[c0];
  float2 w1 = *(const float2*)&wl[128 + c0];
  float2 w2 = *(const float2*)&wl[256 + c0];
  float2 uu = *(const float2*)&wl[384 + c0];
  float2 bb = *(const float2*)&wl[512 + c0];
  int wid = blockIdx.x * 4 + w;
  int nw = gridDim.x * 4;
  float s1x = 0, s1y = 0, s2x = 0, s2y = 0;
  for (int n = wid; n < N_; n += nw) {
    int dg = cnt[n];
    int base = row_ptr[n];
    float a0 = 0, a1 = 0, a2 = 0, sd = 0;
    for (int chunk = 0; chunk < dg; chunk += 64) {
      int cc = min(64, dg - chunk);
      if (lane < cc) {
        float4 v = xp[csr16[base + chunk + lane]];
        a0 += v.x; a1 += v.y; a2 += v.z; sd += v.w;
      }
    }
    #pragma unroll
    for (int m = 1; m < 64; m <<= 1) {
      a0 += __shfl_xor(a0, m);
      a1 += __shfl_xor(a1, m);
      a2 += __shfl_xor(a2, m);
      sd += __shfl_xor(sd, m);
    }
    float4 xn = xp[n];           // premultiplied
    float dn = xn.w;
    a0 += xn.x; a1 += xn.y; a2 += xn.z; sd += xn.w;
    float z0 = dn * a0, z1 = dn * a1, z2 = dn * a2, zw = dn * sd;
    float ox = fmaxf(fmaf(z0, w0.x, fmaf(z1, w1.x, fmaf(z2, w2.x, fmaf(zw, uu.x, bb.x)))), 0.f);
    float oy = fmaxf(fmaf(z0, w0.y, fmaf(z1, w1.y, fmaf(z2, w2.y, fmaf(zw, uu.y, bb.y)))), 0.f);
    s1x += ox; s1y += oy; s2x += ox * ox; s2y += oy * oy;
    *(unsigned int*)&yb[(size_t)n * 128 + c0] = bfpack(ox, oy);
  }
  __shared__ float rs[4][64][4];
  rs[w][lane][0] = s1x; rs[w][lane][1] = s1y;
  rs[w][lane][2] = s2x; rs[w][lane][3] = s2y;
  __syncthreads();
  int s = t >> 7, c = t & 127;
  int lsrc = c >> 1, sl = (s << 1) | (c & 1);
  float a = rs[0][lsrc][sl] + rs[1][lsrc][sl] + rs[2][lsrc][sl] + rs[3][lsrc][sl];
  float* basep = Sp + (blockIdx.x & 7) * 256;
  atomicAdd(&basep[s * 128 + c], a);
}

// hwp = dis[n] * ((y*sc+sh) @ W) -> bf16 premultiplied, CHUNK-MAJOR [4][N+1][32]; sentinel rows
__global__ __launch_bounds__(256) void k_gemm(const unsigned short* __restrict__ yb,
                                              const float* __restrict__ W,
                                              const float* __restrict__ Sp,
                                              const float* __restrict__ g_,
                                              const float* __restrict__ b_,
                                              const float* __restrict__ dis,
                                              unsigned short* __restrict__ hwc, int N_) {
  int t = threadIdx.x;
  if (blockIdx.x == 0 && t < 64) {
    int c = t >> 4, p = t & 15;
    ((unsigned int*)(hwc + ((size_t)c * (N_ + 1) + N_) * 32))[p] = 0;
  }
  __shared__ float scs[128], shs[128];
  __shared__ float yl[64][128];
  if (t < 128) {
    float m_s = 0, v_s = 0;
    #pragma unroll
    for (int p = 0; p < 8; p++) { m_s += Sp[p * 256 + t]; v_s += Sp[p * 256 + 128 + t]; }
    float m = m_s / N_;
    float v = v_s / N_ - m * m;
    float s = g_[t] * rsqrtf(v + NEPS);
    scs[t] = s; shs[t] = b_[t] - m * s;
  }
  __syncthreads();
  int base = blockIdx.x * 64;
  for (int i = t; i < 64 * 16; i += 256) {
    int r = i >> 4;
    int q = (i & 15) * 8;
    int n = base + r;
    float o[8];
    if (n < N_) {
      uint4 v = *(const uint4*)&yb[(size_t)n * 128 + q];
      unsigned int uu[4] = {v.x, v.y, v.z, v.w};
      #pragma unroll
      for (int k = 0; k < 4; k++) {
        o[k * 2]     = fmaf(bflo(uu[k]), scs[q + k * 2],     shs[q + k * 2]);
        o[k * 2 + 1] = fmaf(bfhi(uu[k]), scs[q + k * 2 + 1], shs[q + k * 2 + 1]);
      }
    } else {
      #pragma unroll
      for (int k = 0; k < 8; k++) o[k] = 0.f;
    }
    #pragma unroll
    for (int k = 0; k < 8; k++) yl[r][q + k] = o[k];
  }
  __syncthreads();
  int tn = t >> 5, tj = t & 31;
  float4 acc[8];
  #pragma unroll
  for (int r = 0; r < 8; r++) acc[r] = float4{0, 0, 0, 0};
  for (int kk = 0; kk < 128; kk++) {
    float4 wv = *(const float4*)&W[kk * 128 + tj * 4];
    #pragma unroll
    for (int r = 0; r < 8; r++) {
      float yv = yl[tn * 8 + r][kk];
      acc[r].x = fmaf(yv, wv.x, acc[r].x);
      acc[r].y = fmaf(yv, wv.y, acc[r].y);
      acc[r].z = fmaf(yv, wv.z, acc[r].z);
      acc[r].w = fmaf(yv, wv.w, acc[r].w);
    }
  }
  #pragma unroll
  for (int r = 0; r < 8; r++) {
    int n = base + tn * 8 + r;
    if (n < N_) {
      float dn = dis[n];
      uint2 o;
      o.x = bfpack(acc[r].x * dn, acc[r].y * dn);
      o.y = bfpack(acc[r].z * dn, acc[r].w * dn);
      size_t ro = ((size_t)(tj >> 3) * (N_ + 1) + n) * 32 + (tj & 7) * 4;
      *(uint2*)&hwc[ro] = o;
    }
  }
}

// chunked gather, uint4 lanes: 4 lanes per 64B row, 16 edges per load instruction.
// grid = 4 chunks x 2048 blocks (chunk-major -> 3.2MB chunk fits XCD L2).
template <int FUSE_POOL>
__global__ __launch_bounds__(256) void k_gatherq(const unsigned short* __restrict__ hwc,
                                                 const unsigned short* __restrict__ csr16,
                                                 const int* __restrict__ row_ptr,
                                                 const int* __restrict__ cnt,
                                                 const float* __restrict__ dis,
                                                 const float* __restrict__ bL,
                                                 unsigned short* __restrict__ yb,
                                                 float* __restrict__ Sp,
                                                 const int* __restrict__ batch,
                                                 float* __restrict__ pooled, int N_) {
  int t = threadIdx.x;
  int lane = t & 63, w = t >> 6;
  int g = lane >> 2, sub = lane & 3;           // 16 groups x 4 lanes; row = 4 x uint4
  int chunk = blockIdx.x >> 11;
  int bid = blockIdx.x & 2047;
  int cb8 = chunk * 32 + sub * 8;              // this lane's 8 channels
  const uint4* hwq = (const uint4*)(hwc + (size_t)chunk * (N_ + 1) * 32);
  float bb[8];
  {
    float4 b0 = *(const float4*)&bL[cb8];
    float4 b1 = *(const float4*)&bL[cb8 + 4];
    bb[0] = b0.x; bb[1] = b0.y; bb[2] = b0.z; bb[3] = b0.w;
    bb[4] = b1.x; bb[5] = b1.y; bb[6] = b1.z; bb[7] = b1.w;
  }
  int wid = bid * 4 + w;
  int nw = 2048 * 4;
  float s1[8] = {0, 0, 0, 0, 0, 0, 0, 0}, s2[8] = {0, 0, 0, 0, 0, 0, 0, 0};
  for (int n = wid; n < N_; n += nw) {
    int dg = cnt[n];
    int base = row_ptr[n];
    float acc[8] = {0, 0, 0, 0, 0, 0, 0, 0};
    for (int ch = 0; ch < dg; ch += 64) {
      int cc = min(64, dg - ch);
      int idx = (lane < cc) ? (int)csr16[base + ch + lane] : N_;   // sentinel -> zero row
      int nit = (cc + 15) >> 4;
      #pragma unroll 4
      for (int i = 0; i < nit; i++) {
        int s_ = __shfl(idx, i * 16 + g);
        uint4 v = hwq[(size_t)s_ * 4 + sub];
        acc[0] += bflo(v.x); acc[1] += bfhi(v.x);
        acc[2] += bflo(v.y); acc[3] += bfhi(v.y);
        acc[4] += bflo(v.z); acc[5] += bfhi(v.z);
        acc[6] += bflo(v.w); acc[7] += bfhi(v.w);
      }
    }
    // self row once (group 0 only)
    {
      uint4 v = hwq[(size_t)n * 4 + sub];
      float wc = (g == 0) ? 1.f : 0.f;
      acc[0] = fmaf(wc, bflo(v.x), acc[0]); acc[1] = fmaf(wc, bfhi(v.x), acc[1]);
      acc[2] = fmaf(wc, bflo(v.y), acc[2]); acc[3] = fmaf(wc, bfhi(v.y), acc[3]);
      acc[4] = fmaf(wc, bflo(v.z), acc[4]); acc[5] = fmaf(wc, bfhi(v.z), acc[5]);
      acc[6] = fmaf(wc, bflo(v.w), acc[6]); acc[7] = fmaf(wc, bfhi(v.w), acc[7]);
    }
    #pragma unroll
    for (int k = 0; k < 8; k++) {
      acc[k] += __shfl_xor(acc[k], 4);
      acc[k] += __shfl_xor(acc[k], 8);
      acc[k] += __shfl_xor(acc[k], 16);
      acc[k] += __shfl_xor(acc[k], 32);
    }
    if (g == 0) {
      float dn = dis[n];
      float o[8];
      #pragma unroll
      for (int k = 0; k < 8; k++) {
        o[k] = fmaxf(fmaf(acc[k], dn, bb[k]), 0.f);
        s1[k] += o[k]; s2[k] += o[k] * o[k];
      }
      if (FUSE_POOL) {
        int gg = batch[n];
        #pragma unroll
        for (int k = 0; k < 8; k++) atomicAdd(&pooled[gg * 128 + cb8 + k], o[k]);
      } else {
        uint4 pk;
        pk.x = bfpack(o[0], o[1]); pk.y = bfpack(o[2], o[3]);
        pk.z = bfpack(o[4], o[5]); pk.w = bfpack(o[6], o[7]);
        *(uint4*)&yb[(size_t)n * 128 + cb8] = pk;
      }
    }
  }
  __shared__ float rs[4][4][16];
  if (g == 0) {
    #pragma unroll
    for (int k = 0; k < 8; k++) { rs[w][sub][k] = s1[k]; rs[w][sub][8 + k] = s2[k]; }
  }
  __syncthreads();
  if (t < 64) {
    int ln = t >> 4, k = t & 15;
    float a = rs[0][ln][k] + rs[1][ln][k] + rs[2][ln][k] + rs[3][ln][k];
    int kind = k >> 3;
    int chn = chunk * 32 + ln * 8 + (k & 7);
    atomicAdd(&Sp[(bid & 7) * 256 + kind * 128 + chn], a);
  }
}

__device__ inline int lb_dev(const int* b, int n, int v) {
  int lo = 0, hi = n;
  while (lo < hi) { int mid = (lo + hi) >> 1; if (b[mid] < v) lo = mid + 1; else hi = mid; }
  return lo;
}

// classifier with inline BN3 fold
__global__ void k_cls(const float* __restrict__ pooled, const int* __restrict__ batch,
                      const float* __restrict__ Sp,
                      const float* __restrict__ g_, const float* __restrict__ b_,
                      const float* __restrict__ Wc1, const float* __restrict__ bc1,
                      const float* __restrict__ Wc2, const float* __restrict__ bc2,
                      float* __restrict__ out, int N_, int G_) {
  __shared__ float p[128];
  __shared__ float z[64];
  __shared__ int s_lo, s_hi;
  int g = blockIdx.x, t = threadIdx.x;  // 64 threads
  if (t == 0) s_lo = lb_dev(batch, N_, g);
  if (t == 1) s_hi = lb_dev(batch, N_, g + 1);
  __syncthreads();
  float inv = 1.f / fmaxf((float)(s_hi - s_lo), 1.f);
  for (int k = t; k < 128; k += 64) {
    float m_s = 0, v_s = 0;
    #pragma unroll
    for (int q = 0; q < 8; q++) { m_s += Sp[q * 256 + k]; v_s += Sp[q * 256 + 128 + k]; }
    float m = m_s / N_;
    float v = v_s / N_ - m * m;
    float s = g_[k] * rsqrtf(v + NEPS);
    float sh = b_[k] - m * s;
    p[k] = fmaf(pooled[g * 128 + k] * inv, s, sh);
  }
  __syncthreads();
  float acc = bc1[t];
  for (int k = 0; k < 128; k++) acc = fmaf(p[k], Wc1[k * 64 + t], acc);
  z[t] = fmaxf(acc, 0.f);
  __syncthreads();
  if (t < 2) {
    float o = bc2[t];
    for (int j = 0; j < 64; j++) o = fmaf(z[j], Wc2[j * 2 + t], o);
    out[g * 2 + t] = o;
  }
}

extern "C" void kernel_launch(void* const* d_in, const int* in_sizes, int n_in,
                              void* d_out, int out_size, void* d_ws, size_t ws_size,
                              hipStream_t stream) {
  const float* x    = (const float*)d_in[0];
  const int*   ei   = (const int*)d_in[1];
  const int*   batch= (const int*)d_in[2];
  const float* W1   = (const float*)d_in[3];
  const float* b1   = (const float*)d_in[4];
  const float* W2   = (const float*)d_in[5];
  const float* b2   = (const float*)d_in[6];
  const float* W3   = (const float*)d_in[7];
  const float* b3   = (const float*)d_in[8];
  const float* bn0g = (const float*)d_in[9];
  const float* bn0b = (const float*)d_in[10];
  const float* bn1g = (const float*)d_in[11];
  const float* bn1b = (const float*)d_in[12];
  const float* bn2g = (const float*)d_in[13];
  const float* bn2b = (const float*)d_in[14];
  const float* bn3g = (const float*)d_in[15];
  const float* bn3b = (const float*)d_in[16];
  const float* Wc1  = (const float*)d_in[17];
  const float* bc1  = (const float*)d_in[18];
  const float* Wc2  = (const float*)d_in[19];
  const float* bc2  = (const float*)d_in[20];

  const int N_ = in_sizes[2];
  const int E_ = in_sizes[1] / 2;
  const int G_ = out_size / 2;
  const int NB = (N_ + 255) / 256;   // buckets

  char* ws = (char*)d_ws;
  size_t off = 0;
  auto A = [&](size_t bytes) { size_t o = off; off = (off + bytes + 255) & ~(size_t)255; return o; };
  // zeroed region: gh_pad, stats (BN0 8 floats + 3 layers x 8 partials x 256), pooled
  size_t o_gh    = A(256 * 16 * 4);
  size_t o_stats = A((size_t)(256 + 3 * 2048) * 4);
  size_t o_pool  = A((size_t)G_ * 128 * 4);
  size_t zero_end = off;
  size_t o_cur   = A(256 * 16 * 4);
  size_t o_bbase = A(257 * 4);
  size_t o_kp    = A((size_t)E_ * 4);
  size_t o_csr16 = A(((size_t)E_ + 64) * 2);
  size_t o_rowp  = A((size_t)N_ * 4);
  size_t o_cnt   = A((size_t)N_ * 4);
  size_t o_dis   = A((size_t)N_ * 4);
  size_t o_xp    = A((size_t)N_ * 16);
  size_t o_ybA   = A((size_t)N_ * 128 * 2);              // bf16 activations A
  size_t o_ybB   = A((size_t)N_ * 128 * 2);              // bf16 activations B
  size_t o_hwc   = A((size_t)4 * (N_ + 1) * 32 * 2);     // chunk-major bf16 hw (+sentinels)
  (void)ws_size; (void)n_in;

  int*   gh_pad  = (int*)(ws + o_gh);
  float* stats   = (float*)(ws + o_stats);
  float* Sp1     = stats + 256;
  float* Sp2     = stats + 256 + 2048;
  float* Sp3     = stats + 256 + 4096;
  float* pooled  = (float*)(ws + o_pool);
  int*   cur_pad = (int*)(ws + o_cur);
  int*   b_base  = (int*)(ws + o_bbase);
  unsigned int* kp = (unsigned int*)(ws + o_kp);
  unsigned short* csr16 = (unsigned short*)(ws + o_csr16);
  int*   row_ptr = (int*)(ws + o_rowp);
  int*   cnt     = (int*)(ws + o_cnt);
  float* dis     = (float*)(ws + o_dis);
  float4* xp     = (float4*)(ws + o_xp);
  unsigned short* ybA = (unsigned short*)(ws + o_ybA);
  unsigned short* ybB = (unsigned short*)(ws + o_ybB);
  unsigned short* hwc = (unsigned short*)(ws + o_hwc);

  hipMemsetAsync(ws, 0, zero_end, stream);

  // CSR build: hist -> scan -> partition -> per-bucket sort (+node prep +BN0 stats)
  k_hist<<<256, 256, 0, stream>>>(ei, gh_pad, E_);
  k_scan2<<<1, 256, 0, stream>>>(gh_pad, b_base, cur_pad, E_);
  k_part<<<(E_ + 8191) / 8192, 256, 0, stream>>>(ei, cur_pad, kp, E_);
  k_bucket<<<NB, 256, 0, stream>>>(kp, b_base, csr16, row_ptr, cnt, x, dis, xp, stats, N_);

  // fused layer 1 (BN0 fold + gather + 3->128 GEMM + relu + partial stats) -> bf16 y
  k_layer1<<<2048, 256, 0, stream>>>(xp, csr16, row_ptr, cnt, stats, bn0g, bn0b, W1, b1,
                                     ybA, Sp1, N_);

  // layer 2
  k_gemm<<<(N_ + 63) / 64, 256, 0, stream>>>(ybA, W2, Sp1, bn1g, bn1b, dis, hwc, N_);
  k_gatherq<0><<<4 * 2048, 256, 0, stream>>>(hwc, csr16, row_ptr, cnt, dis, b2, ybB, Sp2,
                                             batch, pooled, N_);

  // layer 3
  k_gemm<<<(N_ + 63) / 64, 256, 0, stream>>>(ybB, W3, Sp2, bn2g, bn2b, dis, hwc, N_);
  k_gatherq<1><<<4 * 2048, 256, 0, stream>>>(hwc, csr16, row_ptr, cnt, dis, b3, nullptr, Sp3,
                                             batch, pooled, N_);

  // classifier (BN3 fold inline)
  k_cls<<<G_, 64, 0, stream>>>(pooled, batch, Sp3, bn3g, bn3b, Wc1, bc1, Wc2, bc2,
                               (float*)d_out, N_, G_);
}

// Round 11
// 318.733 us; speedup vs baseline: 1.6598x; 1.6598x over previous
//
#include <hip/hip_runtime.h>

#define NEPS 1e-5f

__device__ inline unsigned int bfpack(float a, float b) {
  unsigned int ua = __float_as_uint(a), ub = __float_as_uint(b);
  ua += 0x7fff + ((ua >> 16) & 1);
  ub += 0x7fff + ((ub >> 16) & 1);
  return (ua >> 16) | (ub & 0xffff0000u);
}
__device__ inline float bflo(unsigned int u) { return __uint_as_float(u << 16); }
__device__ inline float bfhi(unsigned int u) { return __uint_as_float(u & 0xffff0000u); }

// inclusive scan of v over 256 threads (4 waves); tmp = LDS int[4]
__device__ inline int blockScan256(int v, int t, int* tmp) {
  int lane = t & 63, w = t >> 6;
  #pragma unroll
  for (int off = 1; off < 64; off <<= 1) {
    int u = __shfl_up(v, off);
    if (lane >= off) v += u;
  }
  if (lane == 63) tmp[w] = v;
  __syncthreads();
  int add = 0;
  for (int k = 0; k < w; k++) add += tmp[k];
  return v + add;
}

// ---------------- CSR build via MSB bucket sort (no per-edge global atomics) ----------------
__global__ __launch_bounds__(256) void k_hist(const int* __restrict__ ei,
                                              int* __restrict__ gh_pad, int E_) {
  __shared__ int h[256];
  int t = threadIdx.x;
  h[t] = 0;
  __syncthreads();
  int i = blockIdx.x * 256 + t;
  int stride = gridDim.x * 256;
  for (int e = i; e < E_; e += stride) atomicAdd(&h[ei[E_ + e] >> 8], 1);
  __syncthreads();
  int c = h[t];
  if (c) atomicAdd(&gh_pad[t * 16], c);
}

__global__ __launch_bounds__(256) void k_scan2(const int* __restrict__ gh_pad,
                                               int* __restrict__ b_base,
                                               int* __restrict__ cur_pad, int E_) {
  __shared__ int tmp[4];
  int t = threadIdx.x;
  int c = gh_pad[t * 16];
  int incl = blockScan256(c, t, tmp);
  int excl = incl - c;
  b_base[t] = excl;
  cur_pad[t * 16] = excl;
  if (t == 255) b_base[256] = incl;
}

__global__ __launch_bounds__(256) void k_part(const int* __restrict__ ei,
                                              int* __restrict__ cur_pad,
                                              unsigned int* __restrict__ kp, int E_) {
  __shared__ int lh[256], lbase[256];
  int t = threadIdx.x;
  int start = blockIdx.x * 8192;
  int end = min(start + 8192, E_);
  lh[t] = 0;
  __syncthreads();
  for (int e = start + t; e < end; e += 256) atomicAdd(&lh[ei[E_ + e] >> 8], 1);
  __syncthreads();
  int c = lh[t];
  if (c) lbase[t] = atomicAdd(&cur_pad[t * 16], c);
  __syncthreads();
  lh[t] = 0;
  __syncthreads();
  for (int e = start + t; e < end; e += 256) {
    int d = ei[E_ + e], s = ei[e];
    int bin = d >> 8;
    int slot = atomicAdd(&lh[bin], 1);
    kp[lbase[bin] + slot] = ((unsigned int)d << 16) | (unsigned int)s;
  }
}

__global__ __launch_bounds__(256) void k_bucket(const unsigned int* __restrict__ kp,
                                                const int* __restrict__ b_base,
                                                unsigned short* __restrict__ csr16,
                                                int* __restrict__ row_ptr, int* __restrict__ cnt,
                                                const float* __restrict__ x,
                                                float* __restrict__ dis, float4* __restrict__ xp,
                                                float* __restrict__ stats, int N_) {
  __shared__ int cur[256], offL[256], tmp[4];
  __shared__ float rs[4][8];
  int t = threadIdx.x, b = blockIdx.x;
  int seg0 = b_base[b], seg1 = b_base[b + 1];
  cur[t] = 0;
  __syncthreads();
  for (int e = seg0 + t; e < seg1; e += 256) atomicAdd(&cur[(kp[e] >> 16) & 255], 1);
  __syncthreads();
  int c = cur[t];
  int incl = blockScan256(c, t, tmp);
  offL[t] = incl - c;
  __syncthreads();
  cur[t] = 0;
  __syncthreads();
  for (int e = seg0 + t; e < seg1; e += 256) {
    unsigned int v = kp[e];
    int dl = (v >> 16) & 255;
    int slot = atomicAdd(&cur[dl], 1);
    csr16[seg0 + offL[dl] + slot] = (unsigned short)(v & 0xffffu);
  }
  int n = b * 256 + t;
  float s1[3] = {0, 0, 0}, s2[3] = {0, 0, 0};
  if (n < N_) {
    row_ptr[n] = seg0 + offL[t];
    cnt[n] = c;
    float dg = (float)c + 1.0f;
    float ds_ = rsqrtf(dg);
    dis[n] = ds_;
    float x0 = x[n * 3 + 0], x1 = x[n * 3 + 1], x2 = x[n * 3 + 2];
    float4 v; v.x = ds_ * x0; v.y = ds_ * x1; v.z = ds_ * x2; v.w = ds_;
    xp[n] = v;
    s1[0] = x0; s1[1] = x1; s1[2] = x2;
    s2[0] = x0 * x0; s2[1] = x1 * x1; s2[2] = x2 * x2;
  }
  #pragma unroll
  for (int cc = 0; cc < 3; cc++) {
    for (int off = 32; off > 0; off >>= 1) {
      s1[cc] += __shfl_down(s1[cc], off);
      s2[cc] += __shfl_down(s2[cc], off);
    }
  }
  int lane = t & 63, w = t >> 6;
  if (lane == 0) {
    rs[w][0] = s1[0]; rs[w][1] = s1[1]; rs[w][2] = s1[2]; rs[w][3] = 0.f;
    rs[w][4] = s2[0]; rs[w][5] = s2[1]; rs[w][6] = s2[2]; rs[w][7] = 0.f;
  }
  __syncthreads();
  if (t < 8 && t != 3 && t != 7) {
    float a = rs[0][t] + rs[1][t] + rs[2][t] + rs[3][t];
    atomicAdd(&stats[t], a);
  }
}

// ---------------- fused layer 1: BN0-fold + gather(xp) + GEMM(3->128) + relu + stats ----------------
__global__ __launch_bounds__(256) void k_layer1(const float4* __restrict__ xp,
                                                const unsigned short* __restrict__ csr16,
                                                const int* __restrict__ row_ptr,
                                                const int* __restrict__ cnt,
                                                const float* __restrict__ stats,
                                                const float* __restrict__ g0,
                                                const float* __restrict__ b0,
                                                const float* __restrict__ W1,
                                                const float* __restrict__ b1,
                                                unsigned short* __restrict__ yb,
                                                float* __restrict__ Sp,
                                                int N_) {
  __shared__ float wl[5 * 128];
  int t = threadIdx.x;
  float a_[3], dd_[3];
  #pragma unroll
  for (int c = 0; c < 3; c++) {
    float m = stats[c] / N_;
    float v = stats[4 + c] / N_ - m * m;
    float sc = g0[c] * rsqrtf(v + NEPS);
    a_[c] = sc; dd_[c] = b0[c] - m * sc;
  }
  for (int i = t; i < 384; i += 256) wl[i] = a_[i >> 7] * W1[i];
  for (int i = t; i < 128; i += 256) {
    wl[384 + i] = fmaf(dd_[0], W1[i], fmaf(dd_[1], W1[128 + i], dd_[2] * W1[256 + i]));
    wl[512 + i] = b1[i];
  }
  __syncthreads();
  int lane = t & 63, w = t >> 6;
  int c0 = lane * 2;
  float2 w0 = *(const float2*)&wl[c0];
  float2 w1 = *(const float2*)&wl[128 + c0];
  float2 w2 = *(const float2*)&wl[256 + c0];
  float2 uu = *(const float2*)&wl[384 + c0];
  float2 bb = *(const float2*)&wl[512 + c0];
  int wid = blockIdx.x * 4 + w;
  int nw = gridDim.x * 4;
  float s1x = 0, s1y = 0, s2x = 0, s2y = 0;
  for (int n = wid; n < N_; n += nw) {
    int dg = cnt[n];
    int base = row_ptr[n];
    float a0 = 0, a1 = 0, a2 = 0, sd = 0;
    for (int chunk = 0; chunk < dg; chunk += 64) {
      int cc = min(64, dg - chunk);
      if (lane < cc) {
        float4 v = xp[csr16[base + chunk + lane]];
        a0 += v.x; a1 += v.y; a2 += v.z; sd += v.w;
      }
    }
    #pragma unroll
    for (int m = 1; m < 64; m <<= 1) {
      a0 += __shfl_xor(a0, m);
      a1 += __shfl_xor(a1, m);
      a2 += __shfl_xor(a2, m);
      sd += __shfl_xor(sd, m);
    }
    float4 xn = xp[n];           // premultiplied
    float dn = xn.w;
    a0 += xn.x; a1 += xn.y; a2 += xn.z; sd += xn.w;
    float z0 = dn * a0, z1 = dn * a1, z2 = dn * a2, zw = dn * sd;
    float ox = fmaxf(fmaf(z0, w0.x, fmaf(z1, w1.x, fmaf(z2, w2.x, fmaf(zw, uu.x, bb.x)))), 0.f);
    float oy = fmaxf(fmaf(z0, w0.y, fmaf(z1, w1.y, fmaf(z2, w2.y, fmaf(zw, uu.y, bb.y)))), 0.f);
    s1x += ox; s1y += oy; s2x += ox * ox; s2y += oy * oy;
    *(unsigned int*)&yb[(size_t)n * 128 + c0] = bfpack(ox, oy);
  }
  __shared__ float rs[4][64][4];
  rs[w][lane][0] = s1x; rs[w][lane][1] = s1y;
  rs[w][lane][2] = s2x; rs[w][lane][3] = s2y;
  __syncthreads();
  int s = t >> 7, c = t & 127;
  int lsrc = c >> 1, sl = (s << 1) | (c & 1);
  float a = rs[0][lsrc][sl] + rs[1][lsrc][sl] + rs[2][lsrc][sl] + rs[3][lsrc][sl];
  float* basep = Sp + (blockIdx.x & 7) * 256;
  atomicAdd(&basep[s * 128 + c], a);
}

// hwp = dis[n] * ((y*sc+sh) @ W) -> bf16 premultiplied; y input bf16; sentinel row N_
__global__ __launch_bounds__(256) void k_gemm(const unsigned short* __restrict__ yb,
                                              const float* __restrict__ W,
                                              const float* __restrict__ Sp,
                                              const float* __restrict__ g_,
                                              const float* __restrict__ b_,
                                              const float* __restrict__ dis,
                                              unsigned short* __restrict__ hwb, int N_) {
  int t = threadIdx.x;
  if (blockIdx.x == 0 && t < 64) ((unsigned int*)&hwb[(size_t)N_ * 128])[t] = 0;
  __shared__ float scs[128], shs[128];
  __shared__ float yl[64][128];
  if (t < 128) {
    float m_s = 0, v_s = 0;
    #pragma unroll
    for (int p = 0; p < 8; p++) { m_s += Sp[p * 256 + t]; v_s += Sp[p * 256 + 128 + t]; }
    float m = m_s / N_;
    float v = v_s / N_ - m * m;
    float s = g_[t] * rsqrtf(v + NEPS);
    scs[t] = s; shs[t] = b_[t] - m * s;
  }
  __syncthreads();
  int base = blockIdx.x * 64;
  for (int i = t; i < 64 * 16; i += 256) {
    int r = i >> 4;
    int q = (i & 15) * 8;
    int n = base + r;
    float o[8];
    if (n < N_) {
      uint4 v = *(const uint4*)&yb[(size_t)n * 128 + q];
      unsigned int uu[4] = {v.x, v.y, v.z, v.w};
      #pragma unroll
      for (int k = 0; k < 4; k++) {
        o[k * 2]     = fmaf(bflo(uu[k]), scs[q + k * 2],     shs[q + k * 2]);
        o[k * 2 + 1] = fmaf(bfhi(uu[k]), scs[q + k * 2 + 1], shs[q + k * 2 + 1]);
      }
    } else {
      #pragma unroll
      for (int k = 0; k < 8; k++) o[k] = 0.f;
    }
    #pragma unroll
    for (int k = 0; k < 8; k++) yl[r][q + k] = o[k];
  }
  __syncthreads();
  int tn = t >> 5, tj = t & 31;
  float4 acc[8];
  #pragma unroll
  for (int r = 0; r < 8; r++) acc[r] = float4{0, 0, 0, 0};
  for (int kk = 0; kk < 128; kk++) {
    float4 wv = *(const float4*)&W[kk * 128 + tj * 4];
    #pragma unroll
    for (int r = 0; r < 8; r++) {
      float yv = yl[tn * 8 + r][kk];
      acc[r].x = fmaf(yv, wv.x, acc[r].x);
      acc[r].y = fmaf(yv, wv.y, acc[r].y);
      acc[r].z = fmaf(yv, wv.z, acc[r].z);
      acc[r].w = fmaf(yv, wv.w, acc[r].w);
    }
  }
  #pragma unroll
  for (int r = 0; r < 8; r++) {
    int n = base + tn * 8 + r;
    if (n < N_) {
      float dn = dis[n];
      uint2 o;
      o.x = bfpack(acc[r].x * dn, acc[r].y * dn);
      o.y = bfpack(acc[r].z * dn, acc[r].w * dn);
      *(uint2*)&hwb[(size_t)n * 128 + tj * 4] = o;
    }
  }
}

// gather of premultiplied bf16 rows; bf16 y out; fused partial stats; optional fused pool
template <int FUSE_POOL>
__global__ __launch_bounds__(256) void k_gatherb(const unsigned short* __restrict__ hwb,
                                                 const unsigned short* __restrict__ csr16,
                                                 const int* __restrict__ row_ptr,
                                                 const int* __restrict__ cnt,
                                                 const float* __restrict__ dis,
                                                 const float* __restrict__ bL,
                                                 unsigned short* __restrict__ yb,
                                                 float* __restrict__ Sp,
                                                 const int* __restrict__ batch,
                                                 float* __restrict__ pooled, int N_) {
  int t = threadIdx.x;
  int lane = t & 63, w = t >> 6;
  int g16 = lane >> 4, l16 = lane & 15;
  int c0 = l16 * 8 + g16 * 2;                  // this lane's 2 output channels
  float2 bb = *(const float2*)&bL[c0];
  const uint4* hw4 = (const uint4*)hwb;
  int wid = blockIdx.x * 4 + w;
  int nw = gridDim.x * 4;
  float s1a = 0, s1b = 0, s2a = 0, s2b = 0;
  for (int n = wid; n < N_; n += nw) {
    int dg = cnt[n];
    int base = row_ptr[n];
    float acc[8] = {0, 0, 0, 0, 0, 0, 0, 0};
    for (int chunk = 0; chunk < dg; chunk += 64) {
      int cc = min(64, dg - chunk);
      int idx = (lane < cc) ? (int)csr16[base + chunk + lane] : N_;   // sentinel -> zero row
      int nit = (cc + 3) >> 2;
      #pragma unroll 8
      for (int i = 0; i < nit; i++) {
        int s_ = __shfl(idx, i * 4 + g16);
        uint4 v = hw4[(size_t)s_ * 16 + l16];
        acc[0] += bflo(v.x); acc[1] += bfhi(v.x);
        acc[2] += bflo(v.y); acc[3] += bfhi(v.y);
        acc[4] += bflo(v.z); acc[5] += bfhi(v.z);
        acc[6] += bflo(v.w); acc[7] += bfhi(v.w);
      }
    }
    float dn = dis[n];
    {
      uint4 v = hw4[(size_t)n * 16 + l16];
      float wc = (g16 == 0) ? 1.f : 0.f;
      acc[0] = fmaf(wc, bflo(v.x), acc[0]); acc[1] = fmaf(wc, bfhi(v.x), acc[1]);
      acc[2] = fmaf(wc, bflo(v.y), acc[2]); acc[3] = fmaf(wc, bfhi(v.y), acc[3]);
      acc[4] = fmaf(wc, bflo(v.z), acc[4]); acc[5] = fmaf(wc, bfhi(v.z), acc[5]);
      acc[6] = fmaf(wc, bflo(v.w), acc[6]); acc[7] = fmaf(wc, bfhi(v.w), acc[7]);
    }
    #pragma unroll
    for (int k = 0; k < 8; k++) {
      acc[k] += __shfl_xor(acc[k], 16);
      acc[k] += __shfl_xor(acc[k], 32);
    }
    float ta = (g16 & 1) ? acc[2] : acc[0];
    float tb = (g16 & 1) ? acc[6] : acc[4];
    float va = (g16 & 2) ? tb : ta;
    float tc = (g16 & 1) ? acc[3] : acc[1];
    float td = (g16 & 1) ? acc[7] : acc[5];
    float vb = (g16 & 2) ? td : tc;
    float ox = fmaxf(fmaf(va, dn, bb.x), 0.f);
    float oy = fmaxf(fmaf(vb, dn, bb.y), 0.f);
    s1a += ox; s1b += oy; s2a += ox * ox; s2b += oy * oy;
    if (FUSE_POOL) {
      int g = batch[n];
      atomicAdd(&pooled[g * 128 + c0], ox);
      atomicAdd(&pooled[g * 128 + c0 + 1], oy);
    } else {
      *(unsigned int*)&yb[(size_t)n * 128 + c0] = bfpack(ox, oy);
    }
  }
  __shared__ float rs[4][64][4];
  rs[w][lane][0] = s1a; rs[w][lane][1] = s1b;
  rs[w][lane][2] = s2a; rs[w][lane][3] = s2b;
  __syncthreads();
  int s = t >> 7, c = t & 127;
  int lsrc = (c >> 3) | (((c & 7) >> 1) << 4);
  int sl = (s << 1) | (c & 1);
  float a = rs[0][lsrc][sl] + rs[1][lsrc][sl] + rs[2][lsrc][sl] + rs[3][lsrc][sl];
  float* basep = Sp + (blockIdx.x & 7) * 256;
  atomicAdd(&basep[s * 128 + c], a);
}

__device__ inline int lb_dev(const int* b, int n, int v) {
  int lo = 0, hi = n;
  while (lo < hi) { int mid = (lo + hi) >> 1; if (b[mid] < v) lo = mid + 1; else hi = mid; }
  return lo;
}

// classifier with inline BN3 fold
__global__ void k_cls(const float* __restrict__ pooled, const int* __restrict__ batch,
                      const float* __restrict__ Sp,
                      const float* __restrict__ g_, const float* __restrict__ b_,
                      const float* __restrict__ Wc1, const float* __restrict__ bc1,
                      const float* __restrict__ Wc2, const float* __restrict__ bc2,
                      float* __restrict__ out, int N_, int G_) {
  __shared__ float p[128];
  __shared__ float z[64];
  __shared__ int s_lo, s_hi;
  int g = blockIdx.x, t = threadIdx.x;  // 64 threads
  if (t == 0) s_lo = lb_dev(batch, N_, g);
  if (t == 1) s_hi = lb_dev(batch, N_, g + 1);
  __syncthreads();
  float inv = 1.f / fmaxf((float)(s_hi - s_lo), 1.f);
  for (int k = t; k < 128; k += 64) {
    float m_s = 0, v_s = 0;
    #pragma unroll
    for (int q = 0; q < 8; q++) { m_s += Sp[q * 256 + k]; v_s += Sp[q * 256 + 128 + k]; }
    float m = m_s / N_;
    float v = v_s / N_ - m * m;
    float s = g_[k] * rsqrtf(v + NEPS);
    float sh = b_[k] - m * s;
    p[k] = fmaf(pooled[g * 128 + k] * inv, s, sh);
  }
  __syncthreads();
  float acc = bc1[t];
  for (int k = 0; k < 128; k++) acc = fmaf(p[k], Wc1[k * 64 + t], acc);
  z[t] = fmaxf(acc, 0.f);
  __syncthreads();
  if (t < 2) {
    float o = bc2[t];
    for (int j = 0; j < 64; j++) o = fmaf(z[j], Wc2[j * 2 + t], o);
    out[g * 2 + t] = o;
  }
}

extern "C" void kernel_launch(void* const* d_in, const int* in_sizes, int n_in,
                              void* d_out, int out_size, void* d_ws, size_t ws_size,
                              hipStream_t stream) {
  const float* x    = (const float*)d_in[0];
  const int*   ei   = (const int*)d_in[1];
  const int*   batch= (const int*)d_in[2];
  const float* W1   = (const float*)d_in[3];
  const float* b1   = (const float*)d_in[4];
  const float* W2   = (const float*)d_in[5];
  const float* b2   = (const float*)d_in[6];
  const float* W3   = (const float*)d_in[7];
  const float* b3   = (const float*)d_in[8];
  const float* bn0g = (const float*)d_in[9];
  const float* bn0b = (const float*)d_in[10];
  const float* bn1g = (const float*)d_in[11];
  const float* bn1b = (const float*)d_in[12];
  const float* bn2g = (const float*)d_in[13];
  const float* bn2b = (const float*)d_in[14];
  const float* bn3g = (const float*)d_in[15];
  const float* bn3b = (const float*)d_in[16];
  const float* Wc1  = (const float*)d_in[17];
  const float* bc1  = (const float*)d_in[18];
  const float* Wc2  = (const float*)d_in[19];
  const float* bc2  = (const float*)d_in[20];

  const int N_ = in_sizes[2];
  const int E_ = in_sizes[1] / 2;
  const int G_ = out_size / 2;
  const int NB = (N_ + 255) / 256;   // buckets

  char* ws = (char*)d_ws;
  size_t off = 0;
  auto A = [&](size_t bytes) { size_t o = off; off = (off + bytes + 255) & ~(size_t)255; return o; };
  // zeroed region: gh_pad, stats (BN0 8 floats + 3 layers x 8 partials x 256), pooled
  size_t o_gh    = A(256 * 16 * 4);
  size_t o_stats = A((size_t)(256 + 3 * 2048) * 4);
  size_t o_pool  = A((size_t)G_ * 128 * 4);
  size_t zero_end = off;
  size_t o_cur   = A(256 * 16 * 4);
  size_t o_bbase = A(257 * 4);
  size_t o_kp    = A((size_t)E_ * 4);
  size_t o_csr16 = A(((size_t)E_ + 64) * 2);
  size_t o_rowp  = A((size_t)N_ * 4);
  size_t o_cnt   = A((size_t)N_ * 4);
  size_t o_dis   = A((size_t)N_ * 4);
  size_t o_xp    = A((size_t)N_ * 16);
  size_t o_ybA   = A((size_t)N_ * 128 * 2);          // bf16 activations A
  size_t o_ybB   = A((size_t)N_ * 128 * 2);          // bf16 activations B
  size_t o_bufAh = A(((size_t)N_ + 1) * 128 * 2);    // bf16 premultiplied hw (+sentinel row)
  (void)ws_size; (void)n_in;

  int*   gh_pad  = (int*)(ws + o_gh);
  float* stats   = (float*)(ws + o_stats);
  float* Sp1     = stats + 256;
  float* Sp2     = stats + 256 + 2048;
  float* Sp3     = stats + 256 + 4096;
  float* pooled  = (float*)(ws + o_pool);
  int*   cur_pad = (int*)(ws + o_cur);
  int*   b_base  = (int*)(ws + o_bbase);
  unsigned int* kp = (unsigned int*)(ws + o_kp);
  unsigned short* csr16 = (unsigned short*)(ws + o_csr16);
  int*   row_ptr = (int*)(ws + o_rowp);
  int*   cnt     = (int*)(ws + o_cnt);
  float* dis     = (float*)(ws + o_dis);
  float4* xp     = (float4*)(ws + o_xp);
  unsigned short* ybA = (unsigned short*)(ws + o_ybA);
  unsigned short* ybB = (unsigned short*)(ws + o_ybB);
  unsigned short* bufAh = (unsigned short*)(ws + o_bufAh);

  hipMemsetAsync(ws, 0, zero_end, stream);

  // CSR build: hist -> scan -> partition -> per-bucket sort (+node prep +BN0 stats)
  k_hist<<<256, 256, 0, stream>>>(ei, gh_pad, E_);
  k_scan2<<<1, 256, 0, stream>>>(gh_pad, b_base, cur_pad, E_);
  k_part<<<(E_ + 8191) / 8192, 256, 0, stream>>>(ei, cur_pad, kp, E_);
  k_bucket<<<NB, 256, 0, stream>>>(kp, b_base, csr16, row_ptr, cnt, x, dis, xp, stats, N_);

  // fused layer 1 (BN0 fold + gather + 3->128 GEMM + relu + partial stats) -> bf16 y
  k_layer1<<<2048, 256, 0, stream>>>(xp, csr16, row_ptr, cnt, stats, bn0g, bn0b, W1, b1,
                                     ybA, Sp1, N_);

  // layer 2
  k_gemm<<<(N_ + 63) / 64, 256, 0, stream>>>(ybA, W2, Sp1, bn1g, bn1b, dis, bufAh, N_);
  k_gatherb<0><<<3072, 256, 0, stream>>>(bufAh, csr16, row_ptr, cnt, dis, b2, ybB, Sp2,
                                         batch, pooled, N_);

  // layer 3
  k_gemm<<<(N_ + 63) / 64, 256, 0, stream>>>(ybB, W3, Sp2, bn2g, bn2b, dis, bufAh, N_);
  k_gatherb<1><<<3072, 256, 0, stream>>>(bufAh, csr16, row_ptr, cnt, dis, b3, nullptr, Sp3,
                                         batch, pooled, N_);

  // classifier (BN3 fold inline)
  k_cls<<<G_, 64, 0, stream>>>(pooled, batch, Sp3, bn3g, bn3b, Wc1, bc1, Wc2, bc2,
                               (float*)d_out, N_, G_);
}

// Round 12
// 292.878 us; speedup vs baseline: 1.8063x; 1.0883x over previous
//
#include <hip/hip_runtime.h>

#define NEPS 1e-5f

__device__ inline unsigned int bfpack(float a, float b) {
  unsigned int ua = __float_as_uint(a), ub = __float_as_uint(b);
  ua += 0x7fff + ((ua >> 16) & 1);
  ub += 0x7fff + ((ub >> 16) & 1);
  return (ua >> 16) | (ub & 0xffff0000u);
}
__device__ inline float bflo(unsigned int u) { return __uint_as_float(u << 16); }
__device__ inline float bfhi(unsigned int u) { return __uint_as_float(u & 0xffff0000u); }

// inclusive scan of v over 256 threads (4 waves); tmp = LDS int[4]
__device__ inline int blockScan256(int v, int t, int* tmp) {
  int lane = t & 63, w = t >> 6;
  #pragma unroll
  for (int off = 1; off < 64; off <<= 1) {
    int u = __shfl_up(v, off);
    if (lane >= off) v += u;
  }
  if (lane == 63) tmp[w] = v;
  __syncthreads();
  int add = 0;
  for (int k = 0; k < w; k++) add += tmp[k];
  return v + add;
}

// ---------------- CSR build via MSB bucket sort (no per-edge global atomics) ----------------
__global__ __launch_bounds__(256) void k_hist(const int* __restrict__ ei,
                                              int* __restrict__ gh_pad, int E_) {
  __shared__ int h[256];
  int t = threadIdx.x;
  h[t] = 0;
  __syncthreads();
  int i = blockIdx.x * 256 + t;
  int stride = gridDim.x * 256;
  for (int e = i; e < E_; e += stride) atomicAdd(&h[ei[E_ + e] >> 8], 1);
  __syncthreads();
  int c = h[t];
  if (c) atomicAdd(&gh_pad[t * 16], c);
}

__global__ __launch_bounds__(256) void k_scan2(const int* __restrict__ gh_pad,
                                               int* __restrict__ b_base,
                                               int* __restrict__ cur_pad, int E_) {
  __shared__ int tmp[4];
  int t = threadIdx.x;
  int c = gh_pad[t * 16];
  int incl = blockScan256(c, t, tmp);
  int excl = incl - c;
  b_base[t] = excl;
  cur_pad[t * 16] = excl;
  if (t == 255) b_base[256] = incl;
}

__global__ __launch_bounds__(256) void k_part(const int* __restrict__ ei,
                                              int* __restrict__ cur_pad,
                                              unsigned int* __restrict__ kp, int E_) {
  __shared__ int lh[256], lbase[256];
  int t = threadIdx.x;
  int start = blockIdx.x * 8192;
  int end = min(start + 8192, E_);
  lh[t] = 0;
  __syncthreads();
  for (int e = start + t; e < end; e += 256) atomicAdd(&lh[ei[E_ + e] >> 8], 1);
  __syncthreads();
  int c = lh[t];
  if (c) lbase[t] = atomicAdd(&cur_pad[t * 16], c);
  __syncthreads();
  lh[t] = 0;
  __syncthreads();
  for (int e = start + t; e < end; e += 256) {
    int d = ei[E_ + e], s = ei[e];
    int bin = d >> 8;
    int slot = atomicAdd(&lh[bin], 1);
    kp[lbase[bin] + slot] = ((unsigned int)d << 16) | (unsigned int)s;
  }
}

__global__ __launch_bounds__(256) void k_bucket(const unsigned int* __restrict__ kp,
                                                const int* __restrict__ b_base,
                                                unsigned short* __restrict__ csr16,
                                                int* __restrict__ row_ptr, int* __restrict__ cnt,
                                                const float* __restrict__ x,
                                                float* __restrict__ dis, float4* __restrict__ xp,
                                                float* __restrict__ stats, int N_) {
  __shared__ int cur[256], offL[256], tmp[4];
  __shared__ float rs[4][8];
  int t = threadIdx.x, b = blockIdx.x;
  int seg0 = b_base[b], seg1 = b_base[b + 1];
  cur[t] = 0;
  __syncthreads();
  for (int e = seg0 + t; e < seg1; e += 256) atomicAdd(&cur[(kp[e] >> 16) & 255], 1);
  __syncthreads();
  int c = cur[t];
  int incl = blockScan256(c, t, tmp);
  offL[t] = incl - c;
  __syncthreads();
  cur[t] = 0;
  __syncthreads();
  for (int e = seg0 + t; e < seg1; e += 256) {
    unsigned int v = kp[e];
    int dl = (v >> 16) & 255;
    int slot = atomicAdd(&cur[dl], 1);
    csr16[seg0 + offL[dl] + slot] = (unsigned short)(v & 0xffffu);
  }
  int n = b * 256 + t;
  float s1[3] = {0, 0, 0}, s2[3] = {0, 0, 0};
  if (n < N_) {
    row_ptr[n] = seg0 + offL[t];
    cnt[n] = c;
    float dg = (float)c + 1.0f;
    float ds_ = rsqrtf(dg);
    dis[n] = ds_;
    float x0 = x[n * 3 + 0], x1 = x[n * 3 + 1], x2 = x[n * 3 + 2];
    float4 v; v.x = ds_ * x0; v.y = ds_ * x1; v.z = ds_ * x2; v.w = ds_;
    xp[n] = v;
    s1[0] = x0; s1[1] = x1; s1[2] = x2;
    s2[0] = x0 * x0; s2[1] = x1 * x1; s2[2] = x2 * x2;
  }
  #pragma unroll
  for (int cc = 0; cc < 3; cc++) {
    for (int off = 32; off > 0; off >>= 1) {
      s1[cc] += __shfl_down(s1[cc], off);
      s2[cc] += __shfl_down(s2[cc], off);
    }
  }
  int lane = t & 63, w = t >> 6;
  if (lane == 0) {
    rs[w][0] = s1[0]; rs[w][1] = s1[1]; rs[w][2] = s1[2]; rs[w][3] = 0.f;
    rs[w][4] = s2[0]; rs[w][5] = s2[1]; rs[w][6] = s2[2]; rs[w][7] = 0.f;
  }
  __syncthreads();
  if (t < 8 && t != 3 && t != 7) {
    float a = rs[0][t] + rs[1][t] + rs[2][t] + rs[3][t];
    atomicAdd(&stats[t], a);
  }
}

// ---------------- fused layer 1: BN0-fold + gather(xp) + GEMM(3->128) + relu + stats ----------------
__global__ __launch_bounds__(256) void k_layer1(const float4* __restrict__ xp,
                                                const unsigned short* __restrict__ csr16,
                                                const int* __restrict__ row_ptr,
                                                const int* __restrict__ cnt,
                                                const float* __restrict__ stats,
                                                const float* __restrict__ g0,
                                                const float* __restrict__ b0,
                                                const float* __restrict__ W1,
                                                const float* __restrict__ b1,
                                                unsigned short* __restrict__ yb,
                                                float* __restrict__ Sp,
                                                int N_) {
  __shared__ float wl[5 * 128];
  int t = threadIdx.x;
  float a_[3], dd_[3];
  #pragma unroll
  for (int c = 0; c < 3; c++) {
    float m = stats[c] / N_;
    float v = stats[4 + c] / N_ - m * m;
    float sc = g0[c] * rsqrtf(v + NEPS);
    a_[c] = sc; dd_[c] = b0[c] - m * sc;
  }
  for (int i = t; i < 384; i += 256) wl[i] = a_[i >> 7] * W1[i];
  for (int i = t; i < 128; i += 256) {
    wl[384 + i] = fmaf(dd_[0], W1[i], fmaf(dd_[1], W1[128 + i], dd_[2] * W1[256 + i]));
    wl[512 + i] = b1[i];
  }
  __syncthreads();
  int lane = t & 63, w = t >> 6;
  int c0 = lane * 2;
  float2 w0 = *(const float2*)&wl[c0];
  float2 w1 = *(const float2*)&wl[128 + c0];
  float2 w2 = *(const float2*)&wl[256 + c0];
  float2 uu = *(const float2*)&wl[384 + c0];
  float2 bb = *(const float2*)&wl[512 + c0];
  int wid = blockIdx.x * 4 + w;
  int nw = gridDim.x * 4;
  float s1x = 0, s1y = 0, s2x = 0, s2y = 0;
  for (int n = wid; n < N_; n += nw) {
    int dg = cnt[n];
    int base = row_ptr[n];
    float a0 = 0, a1 = 0, a2 = 0, sd = 0;
    for (int chunk = 0; chunk < dg; chunk += 64) {
      int cc = min(64, dg - chunk);
      if (lane < cc) {
        float4 v = xp[csr16[base + chunk + lane]];
        a0 += v.x; a1 += v.y; a2 += v.z; sd += v.w;
      }
    }
    #pragma unroll
    for (int m = 1; m < 64; m <<= 1) {
      a0 += __shfl_xor(a0, m);
      a1 += __shfl_xor(a1, m);
      a2 += __shfl_xor(a2, m);
      sd += __shfl_xor(sd, m);
    }
    float4 xn = xp[n];           // premultiplied
    float dn = xn.w;
    a0 += xn.x; a1 += xn.y; a2 += xn.z; sd += xn.w;
    float z0 = dn * a0, z1 = dn * a1, z2 = dn * a2, zw = dn * sd;
    float ox = fmaxf(fmaf(z0, w0.x, fmaf(z1, w1.x, fmaf(z2, w2.x, fmaf(zw, uu.x, bb.x)))), 0.f);
    float oy = fmaxf(fmaf(z0, w0.y, fmaf(z1, w1.y, fmaf(z2, w2.y, fmaf(zw, uu.y, bb.y)))), 0.f);
    s1x += ox; s1y += oy; s2x += ox * ox; s2y += oy * oy;
    *(unsigned int*)&yb[(size_t)n * 128 + c0] = bfpack(ox, oy);
  }
  __shared__ float rs[4][64][4];
  rs[w][lane][0] = s1x; rs[w][lane][1] = s1y;
  rs[w][lane][2] = s2x; rs[w][lane][3] = s2y;
  __syncthreads();
  int s = t >> 7, c = t & 127;
  int lsrc = c >> 1, sl = (s << 1) | (c & 1);
  float a = rs[0][lsrc][sl] + rs[1][lsrc][sl] + rs[2][lsrc][sl] + rs[3][lsrc][sl];
  float* basep = Sp + (blockIdx.x & 7) * 256;
  atomicAdd(&basep[s * 128 + c], a);
}

// hwp = dis[n] * ((y*sc+sh) @ W) -> bf16 premultiplied; y input bf16; sentinel row N_
__global__ __launch_bounds__(256) void k_gemm(const unsigned short* __restrict__ yb,
                                              const float* __restrict__ W,
                                              const float* __restrict__ Sp,
                                              const float* __restrict__ g_,
                                              const float* __restrict__ b_,
                                              const float* __restrict__ dis,
                                              unsigned short* __restrict__ hwb, int N_) {
  int t = threadIdx.x;
  if (blockIdx.x == 0 && t < 64) ((unsigned int*)&hwb[(size_t)N_ * 128])[t] = 0;
  __shared__ float scs[128], shs[128];
  __shared__ float yl[64][128];
  if (t < 128) {
    float m_s = 0, v_s = 0;
    #pragma unroll
    for (int p = 0; p < 8; p++) { m_s += Sp[p * 256 + t]; v_s += Sp[p * 256 + 128 + t]; }
    float m = m_s / N_;
    float v = v_s / N_ - m * m;
    float s = g_[t] * rsqrtf(v + NEPS);
    scs[t] = s; shs[t] = b_[t] - m * s;
  }
  __syncthreads();
  int base = blockIdx.x * 64;
  for (int i = t; i < 64 * 16; i += 256) {
    int r = i >> 4;
    int q = (i & 15) * 8;
    int n = base + r;
    float o[8];
    if (n < N_) {
      uint4 v = *(const uint4*)&yb[(size_t)n * 128 + q];
      unsigned int uu[4] = {v.x, v.y, v.z, v.w};
      #pragma unroll
      for (int k = 0; k < 4; k++) {
        o[k * 2]     = fmaf(bflo(uu[k]), scs[q + k * 2],     shs[q + k * 2]);
        o[k * 2 + 1] = fmaf(bfhi(uu[k]), scs[q + k * 2 + 1], shs[q + k * 2 + 1]);
      }
    } else {
      #pragma unroll
      for (int k = 0; k < 8; k++) o[k] = 0.f;
    }
    #pragma unroll
    for (int k = 0; k < 8; k++) yl[r][q + k] = o[k];
  }
  __syncthreads();
  int tn = t >> 5, tj = t & 31;
  float4 acc[8];
  #pragma unroll
  for (int r = 0; r < 8; r++) acc[r] = float4{0, 0, 0, 0};
  for (int kk = 0; kk < 128; kk++) {
    float4 wv = *(const float4*)&W[kk * 128 + tj * 4];
    #pragma unroll
    for (int r = 0; r < 8; r++) {
      float yv = yl[tn * 8 + r][kk];
      acc[r].x = fmaf(yv, wv.x, acc[r].x);
      acc[r].y = fmaf(yv, wv.y, acc[r].y);
      acc[r].z = fmaf(yv, wv.z, acc[r].z);
      acc[r].w = fmaf(yv, wv.w, acc[r].w);
    }
  }
  #pragma unroll
  for (int r = 0; r < 8; r++) {
    int n = base + tn * 8 + r;
    if (n < N_) {
      float dn = dis[n];
      uint2 o;
      o.x = bfpack(acc[r].x * dn, acc[r].y * dn);
      o.y = bfpack(acc[r].z * dn, acc[r].w * dn);
      *(uint2*)&hwb[(size_t)n * 128 + tj * 4] = o;
    }
  }
}

// gather of premultiplied bf16 rows; bf16 y out; fused partial stats; optional fused pool
template <int FUSE_POOL>
__global__ __launch_bounds__(256) void k_gatherb(const unsigned short* __restrict__ hwb,
                                                 const unsigned short* __restrict__ csr16,
                                                 const int* __restrict__ row_ptr,
                                                 const int* __restrict__ cnt,
                                                 const float* __restrict__ dis,
                                                 const float* __restrict__ bL,
                                                 unsigned short* __restrict__ yb,
                                                 float* __restrict__ Sp,
                                                 const int* __restrict__ batch,
                                                 float* __restrict__ pooled, int N_) {
  int t = threadIdx.x;
  int lane = t & 63, w = t >> 6;
  int g16 = lane >> 4, l16 = lane & 15;
  int c0 = l16 * 8 + g16 * 2;                  // this lane's 2 output channels
  float2 bb = *(const float2*)&bL[c0];
  const uint4* hw4 = (const uint4*)hwb;
  int wid = blockIdx.x * 4 + w;
  int nw = gridDim.x * 4;
  float s1a = 0, s1b = 0, s2a = 0, s2b = 0;
  for (int n = wid; n < N_; n += nw) {
    int dg = cnt[n];
    int base = row_ptr[n];
    float acc[8] = {0, 0, 0, 0, 0, 0, 0, 0};
    for (int chunk = 0; chunk < dg; chunk += 64) {
      int cc = min(64, dg - chunk);
      int idx = (lane < cc) ? (int)csr16[base + chunk + lane] : N_;   // sentinel -> zero row
      int nit = (cc + 3) >> 2;
      #pragma unroll 8
      for (int i = 0; i < nit; i++) {
        int s_ = __shfl(idx, i * 4 + g16);
        uint4 v = hw4[(size_t)s_ * 16 + l16];
        acc[0] += bflo(v.x); acc[1] += bfhi(v.x);
        acc[2] += bflo(v.y); acc[3] += bfhi(v.y);
        acc[4] += bflo(v.z); acc[5] += bfhi(v.z);
        acc[6] += bflo(v.w); acc[7] += bfhi(v.w);
      }
    }
    float dn = dis[n];
    {
      uint4 v = hw4[(size_t)n * 16 + l16];
      float wc = (g16 == 0) ? 1.f : 0.f;
      acc[0] = fmaf(wc, bflo(v.x), acc[0]); acc[1] = fmaf(wc, bfhi(v.x), acc[1]);
      acc[2] = fmaf(wc, bflo(v.y), acc[2]); acc[3] = fmaf(wc, bfhi(v.y), acc[3]);
      acc[4] = fmaf(wc, bflo(v.z), acc[4]); acc[5] = fmaf(wc, bfhi(v.z), acc[5]);
      acc[6] = fmaf(wc, bflo(v.w), acc[6]); acc[7] = fmaf(wc, bfhi(v.w), acc[7]);
    }
    #pragma unroll
    for (int k = 0; k < 8; k++) {
      acc[k] += __shfl_xor(acc[k], 16);
      acc[k] += __shfl_xor(acc[k], 32);
    }
    float ta = (g16 & 1) ? acc[2] : acc[0];
    float tb = (g16 & 1) ? acc[6] : acc[4];
    float va = (g16 & 2) ? tb : ta;
    float tc = (g16 & 1) ? acc[3] : acc[1];
    float td = (g16 & 1) ? acc[7] : acc[5];
    float vb = (g16 & 2) ? td : tc;
    float ox = fmaxf(fmaf(va, dn, bb.x), 0.f);
    float oy = fmaxf(fmaf(vb, dn, bb.y), 0.f);
    s1a += ox; s1b += oy; s2a += ox * ox; s2b += oy * oy;
    if (FUSE_POOL) {
      int g = batch[n];
      atomicAdd(&pooled[g * 128 + c0], ox);
      atomicAdd(&pooled[g * 128 + c0 + 1], oy);
    } else {
      *(unsigned int*)&yb[(size_t)n * 128 + c0] = bfpack(ox, oy);
    }
  }
  __shared__ float rs[4][64][4];
  rs[w][lane][0] = s1a; rs[w][lane][1] = s1b;
  rs[w][lane][2] = s2a; rs[w][lane][3] = s2b;
  __syncthreads();
  int s = t >> 7, c = t & 127;
  int lsrc = (c >> 3) | (((c & 7) >> 1) << 4);
  int sl = (s << 1) | (c & 1);
  float a = rs[0][lsrc][sl] + rs[1][lsrc][sl] + rs[2][lsrc][sl] + rs[3][lsrc][sl];
  float* basep = Sp + (blockIdx.x & 7) * 256;
  atomicAdd(&basep[s * 128 + c], a);
}

__device__ inline int lb_dev(const int* b, int n, int v) {
  int lo = 0, hi = n;
  while (lo < hi) { int mid = (lo + hi) >> 1; if (b[mid] < v) lo = mid + 1; else hi = mid; }
  return lo;
}

// classifier with inline BN3 fold
__global__ void k_cls(const float* __restrict__ pooled, const int* __restrict__ batch,
                      const float* __restrict__ Sp,
                      const float* __restrict__ g_, const float* __restrict__ b_,
                      const float* __restrict__ Wc1, const float* __restrict__ bc1,
                      const float* __restrict__ Wc2, const float* __restrict__ bc2,
                      float* __restrict__ out, int N_, int G_) {
  __shared__ float p[128];
  __shared__ float z[64];
  __shared__ int s_lo, s_hi;
  int g = blockIdx.x, t = threadIdx.x;  // 64 threads
  if (t == 0) s_lo = lb_dev(batch, N_, g);
  if (t == 1) s_hi = lb_dev(batch, N_, g + 1);
  __syncthreads();
  float inv = 1.f / fmaxf((float)(s_hi - s_lo), 1.f);
  for (int k = t; k < 128; k += 64) {
    float m_s = 0, v_s = 0;
    #pragma unroll
    for (int q = 0; q < 8; q++) { m_s += Sp[q * 256 + k]; v_s += Sp[q * 256 + 128 + k]; }
    float m = m_s / N_;
    float v = v_s / N_ - m * m;
    float s = g_[k] * rsqrtf(v + NEPS);
    float sh = b_[k] - m * s;
    p[k] = fmaf(pooled[g * 128 + k] * inv, s, sh);
  }
  __syncthreads();
  float acc = bc1[t];
  for (int k = 0; k < 128; k++) acc = fmaf(p[k], Wc1[k * 64 + t], acc);
  z[t] = fmaxf(acc, 0.f);
  __syncthreads();
  if (t < 2) {
    float o = bc2[t];
    for (int j = 0; j < 64; j++) o = fmaf(z[j], Wc2[j * 2 + t], o);
    out[g * 2 + t] = o;
  }
}

extern "C" void kernel_launch(void* const* d_in, const int* in_sizes, int n_in,
                              void* d_out, int out_size, void* d_ws, size_t ws_size,
                              hipStream_t stream) {
  const float* x    = (const float*)d_in[0];
  const int*   ei   = (const int*)d_in[1];
  const int*   batch= (const int*)d_in[2];
  const float* W1   = (const float*)d_in[3];
  const float* b1   = (const float*)d_in[4];
  const float* W2   = (const float*)d_in[5];
  const float* b2   = (const float*)d_in[6];
  const float* W3   = (const float*)d_in[7];
  const float* b3   = (const float*)d_in[8];
  const float* bn0g = (const float*)d_in[9];
  const float* bn0b = (const float*)d_in[10];
  const float* bn1g = (const float*)d_in[11];
  const float* bn1b = (const float*)d_in[12];
  const float* bn2g = (const float*)d_in[13];
  const float* bn2b = (const float*)d_in[14];
  const float* bn3g = (const float*)d_in[15];
  const float* bn3b = (const float*)d_in[16];
  const float* Wc1  = (const float*)d_in[17];
  const float* bc1  = (const float*)d_in[18];
  const float* Wc2  = (const float*)d_in[19];
  const float* bc2  = (const float*)d_in[20];

  const int N_ = in_sizes[2];
  const int E_ = in_sizes[1] / 2;
  const int G_ = out_size / 2;
  const int NB = (N_ + 255) / 256;   // buckets

  char* ws = (char*)d_ws;
  size_t off = 0;
  auto A = [&](size_t bytes) { size_t o = off; off = (off + bytes + 255) & ~(size_t)255; return o; };
  // zeroed region: gh_pad, stats (BN0 8 floats + 3 layers x 8 partials x 256), pooled
  size_t o_gh    = A(256 * 16 * 4);
  size_t o_stats = A((size_t)(256 + 3 * 2048) * 4);
  size_t o_pool  = A((size_t)G_ * 128 * 4);
  size_t zero_end = off;
  size_t o_cur   = A(256 * 16 * 4);
  size_t o_bbase = A(257 * 4);
  size_t o_kp    = A((size_t)E_ * 4);
  size_t o_csr16 = A(((size_t)E_ + 64) * 2);
  size_t o_rowp  = A((size_t)N_ * 4);
  size_t o_cnt   = A((size_t)N_ * 4);
  size_t o_dis   = A((size_t)N_ * 4);
  size_t o_xp    = A((size_t)N_ * 16);
  size_t o_ybA   = A((size_t)N_ * 128 * 2);          // bf16 activations A
  size_t o_ybB   = A((size_t)N_ * 128 * 2);          // bf16 activations B
  size_t o_bufAh = A(((size_t)N_ + 1) * 128 * 2);    // bf16 premultiplied hw (+sentinel row)
  (void)ws_size; (void)n_in;

  int*   gh_pad  = (int*)(ws + o_gh);
  float* stats   = (float*)(ws + o_stats);
  float* Sp1     = stats + 256;
  float* Sp2     = stats + 256 + 2048;
  float* Sp3     = stats + 256 + 4096;
  float* pooled  = (float*)(ws + o_pool);
  int*   cur_pad = (int*)(ws + o_cur);
  int*   b_base  = (int*)(ws + o_bbase);
  unsigned int* kp = (unsigned int*)(ws + o_kp);
  unsigned short* csr16 = (unsigned short*)(ws + o_csr16);
  int*   row_ptr = (int*)(ws + o_rowp);
  int*   cnt     = (int*)(ws + o_cnt);
  float* dis     = (float*)(ws + o_dis);
  float4* xp     = (float4*)(ws + o_xp);
  unsigned short* ybA = (unsigned short*)(ws + o_ybA);
  unsigned short* ybB = (unsigned short*)(ws + o_ybB);
  unsigned short* bufAh = (unsigned short*)(ws + o_bufAh);

  hipMemsetAsync(ws, 0, zero_end, stream);

  // CSR build: hist -> scan -> partition -> per-bucket sort (+node prep +BN0 stats)
  k_hist<<<256, 256, 0, stream>>>(ei, gh_pad, E_);
  k_scan2<<<1, 256, 0, stream>>>(gh_pad, b_base, cur_pad, E_);
  k_part<<<(E_ + 8191) / 8192, 256, 0, stream>>>(ei, cur_pad, kp, E_);
  k_bucket<<<NB, 256, 0, stream>>>(kp, b_base, csr16, row_ptr, cnt, x, dis, xp, stats, N_);

  // fused layer 1 (BN0 fold + gather + 3->128 GEMM + relu + partial stats) -> bf16 y
  k_layer1<<<2048, 256, 0, stream>>>(xp, csr16, row_ptr, cnt, stats, bn0g, bn0b, W1, b1,
                                     ybA, Sp1, N_);

  // layer 2
  k_gemm<<<(N_ + 63) / 64, 256, 0, stream>>>(ybA, W2, Sp1, bn1g, bn1b, dis, bufAh, N_);
  k_gatherb<0><<<2048, 256, 0, stream>>>(bufAh, csr16, row_ptr, cnt, dis, b2, ybB, Sp2,
                                         batch, pooled, N_);

  // layer 3
  k_gemm<<<(N_ + 63) / 64, 256, 0, stream>>>(ybB, W3, Sp2, bn2g, bn2b, dis, bufAh, N_);
  k_gatherb<1><<<2048, 256, 0, stream>>>(bufAh, csr16, row_ptr, cnt, dis, b3, nullptr, Sp3,
                                         batch, pooled, N_);

  // classifier (BN3 fold inline)
  k_cls<<<G_, 64, 0, stream>>>(pooled, batch, Sp3, bn3g, bn3b, Wc1, bc1, Wc2, bc2,
                               (float*)d_out, N_, G_);
}